// Round 6
// baseline (5462.067 us; speedup 1.0000x reference)
//
#include <hip/hip_runtime.h>
#include <hip/hip_bf16.h>
#include <stdint.h>

typedef float  f32x4  __attribute__((ext_vector_type(4)));
typedef short  bf16x8 __attribute__((ext_vector_type(8)));
typedef unsigned int  u32;
typedef unsigned short u16;
typedef unsigned long long u64;

#define BS    64
#define SEQ   1024
#define HID   512

// ---------- helpers ----------
__device__ __forceinline__ u16 f2bf(float f) {
    u32 u = __float_as_uint(f);
    u32 r = (u + 0x7FFFu + ((u >> 16) & 1u)) >> 16;   // RNE
    return (u16)r;
}
__device__ __forceinline__ float bf2f(u16 h) {
    return __uint_as_float(((u32)h) << 16);
}
__device__ __forceinline__ u32 pk2(float a, float b) {
    return (u32)f2bf(a) | ((u32)f2bf(b) << 16);
}
__device__ __forceinline__ float sigm(float x)  { return 1.f / (1.f + __expf(-x)); }
__device__ __forceinline__ float tanh_(float x) { return 1.f - 2.f / (1.f + __expf(2.f * x)); }

// ---------- ws layout ----------
// [0, 2MB)            w4t  bf16 [2048][512]
// [2MB, +8KB)         b4   f32  [2048]
// [.., +256KB)        hbuf u32  [2][4][512*16]  word=(h_bf16<<16)|tag, idx = col*16+row
// [.., +128KB)        cbuf f32  [4][16][512]
// [4MB, ...)          xp   bf16 [64*Tc][2048]
#define OFF_W4T   0
#define OFF_B4    (2u*1024*1024)
#define OFF_HBUF  (OFF_B4 + 8192)
#define OFF_CBUF  (OFF_HBUF + 262144)
#define OFF_XP    (4u*1024*1024)

// ---------- pack W / bias ----------
__global__ void pack_w(const float* __restrict__ Wi, const float* __restrict__ Wf,
                       const float* __restrict__ Wc, const float* __restrict__ Wo,
                       const float* __restrict__ bi, const float* __restrict__ bf_,
                       const float* __restrict__ bc, const float* __restrict__ bo,
                       u16* __restrict__ w4t, float* __restrict__ b4) {
    int n = blockIdx.x;                 // 0..2047
    int gate = n >> 9, c = n & 511;
    const float* W = (gate == 0) ? Wi : (gate == 1) ? Wf : (gate == 2) ? Wc : Wo;
    const float* B = (gate == 0) ? bi : (gate == 1) ? bf_ : (gate == 2) ? bc : bo;
    int k = threadIdx.x * 2;            // 2 per thread
    u32 v = pk2(W[(size_t)k * 512 + c], W[(size_t)(k + 1) * 512 + c]);
    *(u32*)&w4t[(size_t)n * 512 + k] = v;
    if (threadIdx.x == 0) b4[n] = B[c];
}

// ---------- projection GEMM:  xp[m][n] = bf16( x_row(m) . w4t[n] + b4[n] ) ----------
__global__ __launch_bounds__(256, 2)
void gemm_proj(const float* __restrict__ x, const u16* __restrict__ w4t,
               const float* __restrict__ b4, u16* __restrict__ xp,
               int t0, int Tc) {
    __shared__ __align__(16) u16 lA[128 * 64];
    __shared__ __align__(16) u16 lB[128 * 64];

    int ntb = blockIdx.x & 15;
    int mb  = blockIdx.x >> 4;
    int tps = Tc >> 7;                       // tiles per batch strip
    int bstrip = mb / tps, tb = mb % tps;
    const float* Abase = x + (size_t)(bstrip * SEQ + t0 + tb * 128) * 512;
    size_t xprow0 = (size_t)bstrip * Tc + tb * 128;
    int n0 = ntb * 128;

    int tid = threadIdx.x, lane = tid & 63, w = tid >> 6;
    int wm = w >> 1, wn = w & 1;

    f32x4 acc[4][4];
#pragma unroll
    for (int a = 0; a < 4; a++)
#pragma unroll
        for (int b = 0; b < 4; b++) acc[a][b] = (f32x4){0.f, 0.f, 0.f, 0.f};

    for (int kb = 0; kb < 8; kb++) {
        // stage A (fp32 -> bf16)
        {
            int row = tid >> 1, half = tid & 1;
            const float* src = Abase + (size_t)row * 512 + kb * 64 + half * 32;
            u32 tmp[16];
#pragma unroll
            for (int q = 0; q < 8; q++) {
                float4 f = *(const float4*)(src + q * 4);
                tmp[q * 2]     = pk2(f.x, f.y);
                tmp[q * 2 + 1] = pk2(f.z, f.w);
            }
            u16* dst = &lA[row * 64 + half * 32];
#pragma unroll
            for (int q = 0; q < 4; q++)
                *(uint4*)(dst + q * 8) = *(uint4*)&tmp[q * 4];
        }
        // stage B (already bf16)
        {
            int row = tid >> 1, kc = (tid & 1) * 32;
            const u16* src = w4t + (size_t)(n0 + row) * 512 + kb * 64 + kc;
            uint4 v0 = *(const uint4*)(src);
            uint4 v1 = *(const uint4*)(src + 8);
            uint4 v2 = *(const uint4*)(src + 16);
            uint4 v3 = *(const uint4*)(src + 24);
            u16* dst = &lB[row * 64 + kc];
            *(uint4*)(dst) = v0; *(uint4*)(dst + 8) = v1;
            *(uint4*)(dst + 16) = v2; *(uint4*)(dst + 24) = v3;
        }
        __syncthreads();
#pragma unroll
        for (int kt = 0; kt < 2; kt++) {
            bf16x8 a[4], bb[4];
#pragma unroll
            for (int mt = 0; mt < 4; mt++)
                a[mt] = *(const bf16x8*)&lA[(wm * 64 + mt * 16 + (lane & 15)) * 64 + kt * 32 + (lane >> 4) * 8];
#pragma unroll
            for (int nt = 0; nt < 4; nt++)
                bb[nt] = *(const bf16x8*)&lB[(wn * 64 + nt * 16 + (lane & 15)) * 64 + kt * 32 + (lane >> 4) * 8];
#pragma unroll
            for (int mt = 0; mt < 4; mt++)
#pragma unroll
                for (int nt = 0; nt < 4; nt++)
                    acc[mt][nt] = __builtin_amdgcn_mfma_f32_16x16x32_bf16(a[mt], bb[nt], acc[mt][nt], 0, 0, 0);
        }
        __syncthreads();
    }
    // epilogue: + bias, store bf16
#pragma unroll
    for (int nt = 0; nt < 4; nt++) {
        int n = n0 + wn * 64 + nt * 16 + (lane & 15);
        float bv = b4[n];
#pragma unroll
        for (int mt = 0; mt < 4; mt++)
#pragma unroll
            for (int r = 0; r < 4; r++) {
                size_t m = xprow0 + wm * 64 + mt * 16 + (lane >> 4) * 4 + r;
                xp[m * 2048 + n] = f2bf(acc[mt][nt][r] + bv);
            }
    }
}

// ---------- recurrence: tagged-data exchange (intrinsics only) ----------
// 32 WGs x 256 threads: gid = blockIdx>>3 (16 batch rows), q = blockIdx&7 (64 h-cols).
// Wave w owns h-cols [q*64+w*16,+16) for all 4 gates; U slice persistent (ub[16][4],
// lives in AGPRs per gfx950 unified file). hbuf word idx = col*16+row so each
// consumer thread polls 128 CONTIGUOUS bytes (16 u64 relaxed agent loads, no uses
// until the check -> compiler batches them); producer publishes 2 contiguous u64
// tagged stores. Protocol identical to the proven R3 induction: a slot with tag
// T+1 is only overwritten (tag T+3) after every WG consumed tag T+2, which
// requires all WGs past their tag-T+1 poll (barrier between poll and publish).
__global__ __launch_bounds__(256, 1)
void lstm_rec(const float* __restrict__ U0, const float* __restrict__ U1,
              const float* __restrict__ U2, const float* __restrict__ U3,
              const u16* __restrict__ xp, float* __restrict__ out,
              u32* __restrict__ hb, float* __restrict__ cbuf, int t0, int Tc) {
    const int gid = blockIdx.x >> 3;
    const int q   = blockIdx.x & 7;
    const int tid = threadIdx.x;
    const int w = tid >> 6, lane = tid & 63;
    const int col16 = lane & 15;
    const int krow  = lane >> 4;                  // 0..3
    const int mycol = q * 64 + w * 16 + col16;    // h-col 0..511

    __shared__ __align__(16) u16 h_lds[2][16 * 512];   // double-buffered, XOR-swizzled

    // ---- persistent U fragments: ub[kt][gate] ----
    const float* Ug[4] = {U0, U1, U2, U3};
    bf16x8 ub[16][4];
#pragma unroll
    for (int kt = 0; kt < 16; kt++) {
        int kbase = kt * 32 + krow * 8;
#pragma unroll
        for (int g = 0; g < 4; g++) {
            union { u16 sh[8]; bf16x8 v; } uu;
#pragma unroll
            for (int j = 0; j < 8; j++)
                uu.sh[j] = f2bf(Ug[g][(size_t)(kbase + j) * 512 + mycol]);
            ub[kt][g] = uu.v;
        }
    }

    // ---- c state in registers (rows krow*4+r) ----
    float c[4];
    if (t0 == 0) {
        c[0] = c[1] = c[2] = c[3] = 0.f;
    } else {
#pragma unroll
        for (int r = 0; r < 4; r++)
            c[r] = cbuf[((size_t)gid * 16 + krow * 4 + r) * 512 + mycol];
    }

    // ---- xp prefetch for step 0 ----
    u16 xrc[4][4];
#pragma unroll
    for (int g = 0; g < 4; g++)
#pragma unroll
        for (int r = 0; r < 4; r++)
            xrc[g][r] = xp[(size_t)((gid * 16 + krow * 4 + r) * Tc + 0) * 2048
                           + g * 512 + mycol];

    for (int tl = 0; tl < Tc; tl++) {
        const int t = t0 + tl;

        // ---- tagged poll of h_{t-1}: 16 u64 loads over 128 contiguous bytes ----
        // thread tid covers cols {2tid, 2tid+1}, rows 0..15.
        // v[j], j<8 : col 2tid,   rows {2j, 2j+1} (lo,hi u32)
        // v[j], j>=8: col 2tid+1, rows {2(j-8), 2(j-8)+1}
        u64 v[16];
        {
            const u64* src = (const u64*)((const char*)hb
                              + (((size_t)((t + 1) & 1) * 4 + gid) << 15)
                              + (size_t)tid * 128);
            const u32 te = (u32)t & 0xFFFFu;
            for (;;) {
#pragma unroll
                for (int j = 0; j < 16; j++)
                    v[j] = __hip_atomic_load(src + j, __ATOMIC_RELAXED,
                                             __HIP_MEMORY_SCOPE_AGENT);
                u32 bad = 0;
#pragma unroll
                for (int j = 0; j < 16; j++) {
                    bad |= (((u32)v[j]) ^ te) & 0xFFFFu;
                    bad |= (((u32)(v[j] >> 32)) ^ te) & 0xFFFFu;
                }
                if (!bad) break;
            }
        }

        // ---- stage to LDS (buffer t&1), swizzled ----
        u16* hl = &h_lds[t & 1][0];
#pragma unroll
        for (int R = 0; R < 16; R++) {
            u32 lo = (R & 1) ? (u32)(v[R >> 1] >> 32)       : (u32)v[R >> 1];
            u32 hi = (R & 1) ? (u32)(v[8 + (R >> 1)] >> 32) : (u32)v[8 + (R >> 1)];
            u32 packed = (lo >> 16) | (hi & 0xFFFF0000u);
            u32 byte = ((u32)(R * 1024) + (u32)(tid * 4)) ^ ((u32)(R & 7) << 4);
            *(u32*)((char*)hl + byte) = packed;
        }
        __syncthreads();

        // ---- prefetch xp for next step (hidden under MFMA+gates+next poll) ----
        u16 xrn[4][4];
        {
            int tln = (tl + 1 < Tc) ? (tl + 1) : tl;
#pragma unroll
            for (int g = 0; g < 4; g++)
#pragma unroll
                for (int r = 0; r < 4; r++)
                    xrn[g][r] = xp[(size_t)((gid * 16 + krow * 4 + r) * Tc + tln) * 2048
                                   + g * 512 + mycol];
        }

        // ---- z = h @ U : 64 MFMAs/wave, gates in-register ----
        f32x4 acc[4];
#pragma unroll
        for (int g = 0; g < 4; g++) acc[g] = (f32x4){0.f, 0.f, 0.f, 0.f};
#pragma unroll
        for (int kt = 0; kt < 16; kt++) {
            u32 byte = ((u32)(col16 * 1024) + (u32)(kt * 64) + (u32)(krow * 16))
                       ^ ((u32)(col16 & 7) << 4);
            bf16x8 af = *(const bf16x8*)((const char*)hl + byte);
#pragma unroll
            for (int g = 0; g < 4; g++)
                acc[g] = __builtin_amdgcn_mfma_f32_16x16x32_bf16(af, ub[kt][g], acc[g], 0, 0, 0);
        }

        // ---- gates ----
        float hv[4];
#pragma unroll
        for (int r = 0; r < 4; r++) {
            float zi = acc[0][r] + bf2f(xrc[0][r]);
            float zf = acc[1][r] + bf2f(xrc[1][r]);
            float zg = acc[2][r] + bf2f(xrc[2][r]);
            float zo = acc[3][r] + bf2f(xrc[3][r]);
            float iv = fmaxf(zi, 0.f), fv = fmaxf(zf, 0.f);
            float gv = tanh_(zg), ov = sigm(zo);
            c[r] = fv * c[r] + iv * gv;
            hv[r] = ov * tanh_(c[r]);
        }

        // ---- publish tagged h_t: 2 contiguous u64 relaxed agent stores ----
        {
            const u32 tag = (u32)((t + 1) & 0xFFFF);
            u32 w0 = ((u32)f2bf(hv[0]) << 16) | tag;
            u32 w1 = ((u32)f2bf(hv[1]) << 16) | tag;
            u32 w2 = ((u32)f2bf(hv[2]) << 16) | tag;
            u32 w3 = ((u32)f2bf(hv[3]) << 16) | tag;
            u64* dst = (u64*)((char*)hb + (((size_t)(t & 1) * 4 + gid) << 15)
                              + ((size_t)mycol * 64 + krow * 16));
            __hip_atomic_store(dst,     (u64)w0 | ((u64)w1 << 32),
                               __ATOMIC_RELAXED, __HIP_MEMORY_SCOPE_AGENT);
            __hip_atomic_store(dst + 1, (u64)w2 | ((u64)w3 << 32),
                               __ATOMIC_RELAXED, __HIP_MEMORY_SCOPE_AGENT);
        }

        // ---- output stores (off critical path) ----
#pragma unroll
        for (int r = 0; r < 4; r++)
            out[(size_t)((gid * 16 + krow * 4 + r) * SEQ + t) * 512 + mycol] = hv[r];

        // rotate xp registers
#pragma unroll
        for (int g = 0; g < 4; g++)
#pragma unroll
            for (int r = 0; r < 4; r++) xrc[g][r] = xrn[g][r];
    }

    // save c for next chunk
#pragma unroll
    for (int r = 0; r < 4; r++)
        cbuf[((size_t)gid * 16 + krow * 4 + r) * 512 + mycol] = c[r];
}

// ---------- launch ----------
extern "C" void kernel_launch(void* const* d_in, const int* in_sizes, int n_in,
                              void* d_out, int out_size, void* d_ws, size_t ws_size,
                              hipStream_t stream) {
    const float* x  = (const float*)d_in[0];
    const float* Wg[4] = {(const float*)d_in[1], (const float*)d_in[4],
                          (const float*)d_in[7], (const float*)d_in[10]};
    const float* Ug[4] = {(const float*)d_in[2], (const float*)d_in[5],
                          (const float*)d_in[8], (const float*)d_in[11]};
    const float* Bg[4] = {(const float*)d_in[3], (const float*)d_in[6],
                          (const float*)d_in[9], (const float*)d_in[12]};
    float* out = (float*)d_out;

    char* ws = (char*)d_ws;
    u16*   w4t   = (u16*)(ws + OFF_W4T);
    float* b4    = (float*)(ws + OFF_B4);
    u32*   hb    = (u32*)(ws + OFF_HBUF);
    float* cbuf  = (float*)(ws + OFF_CBUF);
    u16*   xp    = (u16*)(ws + OFF_XP);

    // pick chunk length that fits ws
    int Tc = 128;
    for (int c = 1024; c >= 128; c >>= 1)
        if ((size_t)OFF_XP + (size_t)BS * c * 2048 * 2 <= ws_size) { Tc = c; break; }

    // zero tagged hbuf: tag 0 == "h_{-1} ready, value 0"
    hipMemsetAsync(ws + OFF_HBUF, 0, 262144, stream);

    pack_w<<<2048, 256, 0, stream>>>(Wg[0], Wg[1], Wg[2], Wg[3],
                                     Bg[0], Bg[1], Bg[2], Bg[3], w4t, b4);

    for (int t0 = 0; t0 < SEQ; t0 += Tc) {
        dim3 ggrid((unsigned)(BS * (Tc / 128) * 16));
        gemm_proj<<<ggrid, 256, 0, stream>>>(x, w4t, b4, xp, t0, Tc);
        lstm_rec<<<32, 256, 0, stream>>>(Ug[0], Ug[1], Ug[2], Ug[3],
                                         xp, out, hb, cbuf, t0, Tc);
    }
}

// Round 7
// 3938.704 us; speedup vs baseline: 1.3868x; 1.3868x over previous
//
#include <hip/hip_runtime.h>
#include <hip/hip_bf16.h>
#include <stdint.h>

typedef float  f32x4  __attribute__((ext_vector_type(4)));
typedef short  bf16x8 __attribute__((ext_vector_type(8)));
typedef unsigned int  u32;
typedef unsigned short u16;
typedef unsigned long long u64;

#define BS    64
#define SEQ   1024
#define HID   512

// ---------- helpers ----------
__device__ __forceinline__ u16 f2bf(float f) {
    u32 u = __float_as_uint(f);
    u32 r = (u + 0x7FFFu + ((u >> 16) & 1u)) >> 16;   // RNE
    return (u16)r;
}
__device__ __forceinline__ float bf2f(u16 h) {
    return __uint_as_float(((u32)h) << 16);
}
__device__ __forceinline__ u32 pk2(float a, float b) {
    return (u32)f2bf(a) | ((u32)f2bf(b) << 16);
}
__device__ __forceinline__ float sigm(float x)  { return 1.f / (1.f + __expf(-x)); }
__device__ __forceinline__ float tanh_(float x) { return 1.f - 2.f / (1.f + __expf(2.f * x)); }

// ---------- ws layout ----------
// [0, 2MB)            w4t  bf16 [2048][512]
// [2MB, +8KB)         b4   f32  [2048]
// [.., +128KB)        hd   u32  [2][4][16][256]  plain packed bf16 h (2 cols/u32)
// [.., +256B)         tg   u32  [4][16]          per-(gid,q) monotonic tags (64B/gid)
// [.., +128KB)        cbuf f32  [4][16][512]
// [4MB, ...)          xp   bf16 [64*Tc][2048]
#define OFF_W4T   0
#define OFF_B4    (2u*1024*1024)
#define OFF_HD    (OFF_B4 + 8192)
#define OFF_TG    (OFF_HD + 131072)
#define OFF_CBUF  (OFF_HD + 262144)
#define OFF_XP    (4u*1024*1024)

// ---------- pack W / bias ----------
__global__ void pack_w(const float* __restrict__ Wi, const float* __restrict__ Wf,
                       const float* __restrict__ Wc, const float* __restrict__ Wo,
                       const float* __restrict__ bi, const float* __restrict__ bf_,
                       const float* __restrict__ bc, const float* __restrict__ bo,
                       u16* __restrict__ w4t, float* __restrict__ b4) {
    int n = blockIdx.x;                 // 0..2047
    int gate = n >> 9, c = n & 511;
    const float* W = (gate == 0) ? Wi : (gate == 1) ? Wf : (gate == 2) ? Wc : Wo;
    const float* B = (gate == 0) ? bi : (gate == 1) ? bf_ : (gate == 2) ? bc : bo;
    int k = threadIdx.x * 2;            // 2 per thread
    u32 v = pk2(W[(size_t)k * 512 + c], W[(size_t)(k + 1) * 512 + c]);
    *(u32*)&w4t[(size_t)n * 512 + k] = v;
    if (threadIdx.x == 0) b4[n] = B[c];
}

// ---------- projection GEMM:  xp[m][n] = bf16( x_row(m) . w4t[n] + b4[n] ) ----------
__global__ __launch_bounds__(256, 2)
void gemm_proj(const float* __restrict__ x, const u16* __restrict__ w4t,
               const float* __restrict__ b4, u16* __restrict__ xp,
               int t0, int Tc) {
    __shared__ __align__(16) u16 lA[128 * 64];
    __shared__ __align__(16) u16 lB[128 * 64];

    int ntb = blockIdx.x & 15;
    int mb  = blockIdx.x >> 4;
    int tps = Tc >> 7;                       // tiles per batch strip
    int bstrip = mb / tps, tb = mb % tps;
    const float* Abase = x + (size_t)(bstrip * SEQ + t0 + tb * 128) * 512;
    size_t xprow0 = (size_t)bstrip * Tc + tb * 128;
    int n0 = ntb * 128;

    int tid = threadIdx.x, lane = tid & 63, w = tid >> 6;
    int wm = w >> 1, wn = w & 1;

    f32x4 acc[4][4];
#pragma unroll
    for (int a = 0; a < 4; a++)
#pragma unroll
        for (int b = 0; b < 4; b++) acc[a][b] = (f32x4){0.f, 0.f, 0.f, 0.f};

    for (int kb = 0; kb < 8; kb++) {
        // stage A (fp32 -> bf16)
        {
            int row = tid >> 1, half = tid & 1;
            const float* src = Abase + (size_t)row * 512 + kb * 64 + half * 32;
            u32 tmp[16];
#pragma unroll
            for (int q = 0; q < 8; q++) {
                float4 f = *(const float4*)(src + q * 4);
                tmp[q * 2]     = pk2(f.x, f.y);
                tmp[q * 2 + 1] = pk2(f.z, f.w);
            }
            u16* dst = &lA[row * 64 + half * 32];
#pragma unroll
            for (int q = 0; q < 4; q++)
                *(uint4*)(dst + q * 8) = *(uint4*)&tmp[q * 4];
        }
        // stage B (already bf16)
        {
            int row = tid >> 1, kc = (tid & 1) * 32;
            const u16* src = w4t + (size_t)(n0 + row) * 512 + kb * 64 + kc;
            uint4 v0 = *(const uint4*)(src);
            uint4 v1 = *(const uint4*)(src + 8);
            uint4 v2 = *(const uint4*)(src + 16);
            uint4 v3 = *(const uint4*)(src + 24);
            u16* dst = &lB[row * 64 + kc];
            *(uint4*)(dst) = v0; *(uint4*)(dst + 8) = v1;
            *(uint4*)(dst + 16) = v2; *(uint4*)(dst + 24) = v3;
        }
        __syncthreads();
#pragma unroll
        for (int kt = 0; kt < 2; kt++) {
            bf16x8 a[4], bb[4];
#pragma unroll
            for (int mt = 0; mt < 4; mt++)
                a[mt] = *(const bf16x8*)&lA[(wm * 64 + mt * 16 + (lane & 15)) * 64 + kt * 32 + (lane >> 4) * 8];
#pragma unroll
            for (int nt = 0; nt < 4; nt++)
                bb[nt] = *(const bf16x8*)&lB[(wn * 64 + nt * 16 + (lane & 15)) * 64 + kt * 32 + (lane >> 4) * 8];
#pragma unroll
            for (int mt = 0; mt < 4; mt++)
#pragma unroll
                for (int nt = 0; nt < 4; nt++)
                    acc[mt][nt] = __builtin_amdgcn_mfma_f32_16x16x32_bf16(a[mt], bb[nt], acc[mt][nt], 0, 0, 0);
        }
        __syncthreads();
    }
    // epilogue: + bias, store bf16
#pragma unroll
    for (int nt = 0; nt < 4; nt++) {
        int n = n0 + wn * 64 + nt * 16 + (lane & 15);
        float bv = b4[n];
#pragma unroll
        for (int mt = 0; mt < 4; mt++)
#pragma unroll
            for (int r = 0; r < 4; r++) {
                size_t m = xprow0 + wm * 64 + mt * 16 + (lane >> 4) * 4 + r;
                xp[m * 2048 + n] = f2bf(acc[mt][nt][r] + bv);
            }
    }
}

// ---------- recurrence: split tag + data exchange ----------
// 32 WGs x 256 threads: gid = blockIdx>>3 (16 batch rows), q = blockIdx&7 (64 h-cols).
// Wave w owns h-cols [q*64+w*16,+16) for all 4 gates; U slice persistent (ub[16][4]).
// Publish: plain packed-bf16 data stores (agent atomics) -> __syncthreads() (hipcc
// emits s_waitcnt vmcnt(0) before s_barrier => all 256 threads' stores ack'd at the
// coherence point) -> thread 0 stores tag (t+1). Consume: spin on the 64B tag line
// (8 tags, one cache line, ~zero BW) until all >= t, then ONE coalesced 16KB
// agent-scope read (per instruction, lanes are 8B apart = fully coalesced).
// Tags are monotonic (no resets) -> deadlock-free, chunk-safe, graph-replay-safe.
__global__ __launch_bounds__(256, 1)
void lstm_rec(const float* __restrict__ U0, const float* __restrict__ U1,
              const float* __restrict__ U2, const float* __restrict__ U3,
              const u16* __restrict__ xp, float* __restrict__ out,
              u32* __restrict__ hd, u32* __restrict__ tg,
              float* __restrict__ cbuf, int t0, int Tc) {
    const int gid = blockIdx.x >> 3;
    const int q   = blockIdx.x & 7;
    const int tid = threadIdx.x;
    const int w = tid >> 6, lane = tid & 63;
    const int col16 = lane & 15;
    const int krow  = lane >> 4;                  // 0..3
    const int mycol = q * 64 + w * 16 + col16;    // h-col 0..511

    __shared__ __align__(16) u16 h_lds[2][16 * 512];   // double-buffered, XOR-swizzled

    // ---- persistent U fragments: ub[kt][gate] ----
    const float* Ug[4] = {U0, U1, U2, U3};
    bf16x8 ub[16][4];
#pragma unroll
    for (int kt = 0; kt < 16; kt++) {
        int kbase = kt * 32 + krow * 8;
#pragma unroll
        for (int g = 0; g < 4; g++) {
            union { u16 sh[8]; bf16x8 v; } uu;
#pragma unroll
            for (int j = 0; j < 8; j++)
                uu.sh[j] = f2bf(Ug[g][(size_t)(kbase + j) * 512 + mycol]);
            ub[kt][g] = uu.v;
        }
    }

    // ---- c state in registers (rows krow*4+r) ----
    float c[4];
    if (t0 == 0) {
        c[0] = c[1] = c[2] = c[3] = 0.f;
    } else {
#pragma unroll
        for (int r = 0; r < 4; r++)
            c[r] = cbuf[((size_t)gid * 16 + krow * 4 + r) * 512 + mycol];
    }

    // ---- xp prefetch for step 0 ----
    u16 xrc[4][4];
#pragma unroll
    for (int g = 0; g < 4; g++)
#pragma unroll
        for (int r = 0; r < 4; r++)
            xrc[g][r] = xp[(size_t)((gid * 16 + krow * 4 + r) * Tc + 0) * 2048
                           + g * 512 + mycol];

    const u64* tagp = (const u64*)(tg + gid * 16);

    for (int tl = 0; tl < Tc; tl++) {
        const int t = t0 + tl;

        // ---- poll the 64B tag line until all 8 producers published step t ----
        {
            const u32 te = (u32)t;
            for (;;) {
                u64 a0 = __hip_atomic_load(tagp + 0, __ATOMIC_RELAXED, __HIP_MEMORY_SCOPE_AGENT);
                u64 a1 = __hip_atomic_load(tagp + 1, __ATOMIC_RELAXED, __HIP_MEMORY_SCOPE_AGENT);
                u64 a2 = __hip_atomic_load(tagp + 2, __ATOMIC_RELAXED, __HIP_MEMORY_SCOPE_AGENT);
                u64 a3 = __hip_atomic_load(tagp + 3, __ATOMIC_RELAXED, __HIP_MEMORY_SCOPE_AGENT);
                bool ok = ((u32)a0 >= te) & ((u32)(a0 >> 32) >= te)
                        & ((u32)a1 >= te) & ((u32)(a1 >> 32) >= te)
                        & ((u32)a2 >= te) & ((u32)(a2 >> 32) >= te)
                        & ((u32)a3 >= te) & ((u32)(a3 >> 32) >= te);
                if (ok) break;
            }
        }

        // ---- xp prefetch for next step (hides under data load + MFMA) ----
        u16 xrn[4][4];
        {
            int tln = (tl + 1 < Tc) ? (tl + 1) : tl;
#pragma unroll
            for (int g = 0; g < 4; g++)
#pragma unroll
                for (int r = 0; r < 4; r++)
                    xrn[g][r] = xp[(size_t)((gid * 16 + krow * 4 + r) * Tc + tln) * 2048
                                   + g * 512 + mycol];
        }

        // ---- one coalesced 16KB read of h_{t-1} (8 x u64, lanes 8B apart) ----
        u64 v[8];
        {
            const u64* src = (const u64*)hd
                             + (((size_t)(((t + 1) & 1) * 4 + gid)) << 11) + tid;
#pragma unroll
            for (int j = 0; j < 8; j++)
                v[j] = __hip_atomic_load(src + j * 256, __ATOMIC_RELAXED,
                                         __HIP_MEMORY_SCOPE_AGENT);
        }

        // ---- stage to LDS (buffer t&1), swizzled ----
        // u64 idx W = j*256+tid -> row = 2j + (tid>>7), cols 4*(tid&127)..+3
        u16* hl = &h_lds[t & 1][0];
#pragma unroll
        for (int j = 0; j < 8; j++) {
            u32 row = 2 * j + (tid >> 7);
            u32 byte = (row * 1024 + (u32)(tid & 127) * 8) ^ ((row & 7) << 4);
            *(u64*)((char*)hl + byte) = v[j];
        }
        __syncthreads();

        // ---- z = h @ U : 64 MFMAs/wave, gates in-register ----
        f32x4 acc[4];
#pragma unroll
        for (int g = 0; g < 4; g++) acc[g] = (f32x4){0.f, 0.f, 0.f, 0.f};
#pragma unroll
        for (int kt = 0; kt < 16; kt++) {
            u32 byte = ((u32)(col16 * 1024) + (u32)(kt * 64) + (u32)(krow * 16))
                       ^ ((u32)(col16 & 7) << 4);
            bf16x8 af = *(const bf16x8*)((const char*)hl + byte);
#pragma unroll
            for (int g = 0; g < 4; g++)
                acc[g] = __builtin_amdgcn_mfma_f32_16x16x32_bf16(af, ub[kt][g], acc[g], 0, 0, 0);
        }

        // ---- gates ----
        float hv[4];
#pragma unroll
        for (int r = 0; r < 4; r++) {
            float zi = acc[0][r] + bf2f(xrc[0][r]);
            float zf = acc[1][r] + bf2f(xrc[1][r]);
            float zg = acc[2][r] + bf2f(xrc[2][r]);
            float zo = acc[3][r] + bf2f(xrc[3][r]);
            float iv = fmaxf(zi, 0.f), fv = fmaxf(zf, 0.f);
            float gv = tanh_(zg), ov = sigm(zo);
            c[r] = fv * c[r] + iv * gv;
            hv[r] = ov * tanh_(c[r]);
        }

        // ---- publish data: pack col-pairs via shfl, even lanes store u32 ----
        {
            u32 base = ((u32)(t & 1) * 4 + (u32)gid) << 12;   // u32 words
#pragma unroll
            for (int r = 0; r < 4; r++) {
                u16 hb16 = f2bf(hv[r]);
                u32 other = (u32)(unsigned)__shfl_xor((int)(u32)hb16, 1);
                if (!(lane & 1)) {
                    u32 packed = (u32)hb16 | (other << 16);
                    int row = krow * 4 + r;
                    __hip_atomic_store(hd + base + row * 256 + (mycol >> 1), packed,
                                       __ATOMIC_RELAXED, __HIP_MEMORY_SCOPE_AGENT);
                }
            }
        }
        __syncthreads();   // vmcnt(0) before s_barrier: all data stores ack'd at MALL

        // ---- publish tag, then off-critical-path out stores ----
        if (tid == 0)
            __hip_atomic_store(tg + gid * 16 + q, (u32)(t + 1),
                               __ATOMIC_RELAXED, __HIP_MEMORY_SCOPE_AGENT);
#pragma unroll
        for (int r = 0; r < 4; r++)
            out[(size_t)((gid * 16 + krow * 4 + r) * SEQ + t) * 512 + mycol] = hv[r];

        // rotate xp registers
#pragma unroll
        for (int g = 0; g < 4; g++)
#pragma unroll
            for (int r = 0; r < 4; r++) xrc[g][r] = xrn[g][r];
    }

    // save c for next chunk
#pragma unroll
    for (int r = 0; r < 4; r++)
        cbuf[((size_t)gid * 16 + krow * 4 + r) * 512 + mycol] = c[r];
}

// ---------- launch ----------
extern "C" void kernel_launch(void* const* d_in, const int* in_sizes, int n_in,
                              void* d_out, int out_size, void* d_ws, size_t ws_size,
                              hipStream_t stream) {
    const float* x  = (const float*)d_in[0];
    const float* Wg[4] = {(const float*)d_in[1], (const float*)d_in[4],
                          (const float*)d_in[7], (const float*)d_in[10]};
    const float* Ug[4] = {(const float*)d_in[2], (const float*)d_in[5],
                          (const float*)d_in[8], (const float*)d_in[11]};
    const float* Bg[4] = {(const float*)d_in[3], (const float*)d_in[6],
                          (const float*)d_in[9], (const float*)d_in[12]};
    float* out = (float*)d_out;

    char* ws = (char*)d_ws;
    u16*   w4t   = (u16*)(ws + OFF_W4T);
    float* b4    = (float*)(ws + OFF_B4);
    u32*   hd    = (u32*)(ws + OFF_HD);
    u32*   tg    = (u32*)(ws + OFF_TG);
    float* cbuf  = (float*)(ws + OFF_CBUF);
    u16*   xp    = (u16*)(ws + OFF_XP);

    // pick chunk length that fits ws
    int Tc = 128;
    for (int c = 1024; c >= 128; c >>= 1)
        if ((size_t)OFF_XP + (size_t)BS * c * 2048 * 2 <= ws_size) { Tc = c; break; }

    // zero h data (h_{-1}=0) + tags (tag 0 == "h_{-1} ready")
    hipMemsetAsync(ws + OFF_HD, 0, 131072 + 4096, stream);

    pack_w<<<2048, 256, 0, stream>>>(Wg[0], Wg[1], Wg[2], Wg[3],
                                     Bg[0], Bg[1], Bg[2], Bg[3], w4t, b4);

    for (int t0 = 0; t0 < SEQ; t0 += Tc) {
        dim3 ggrid((unsigned)(BS * (Tc / 128) * 16));
        gemm_proj<<<ggrid, 256, 0, stream>>>(x, w4t, b4, xp, t0, Tc);
        lstm_rec<<<32, 256, 0, stream>>>(Ug[0], Ug[1], Ug[2], Ug[3],
                                         xp, out, hd, tg, cbuf, t0, Tc);
    }
}